// Round 2
// baseline (258.600 us; speedup 1.0000x reference)
//
#include <hip/hip_runtime.h>
#include <hip/hip_bf16.h>

// Retention: out = (tril(alpha^(i-j)) * (QK^T/sqrt(d))) @ V, qkv = x@W + b
// Decay folded into operands: Q' = q*alpha^i/sqrt(d), K' = k*alpha^(-j)
// All GEMMs: m97 structure (128x128 tile, BK=64, global_load_lds dwordx4,
// linear [128][64] LDS, 2-barrier k-loop).

#define SEQ   1024
#define DIM   768
#define ND3   2304
#define GROUP 8

typedef __attribute__((ext_vector_type(8))) short bf16x8;
typedef __attribute__((ext_vector_type(4))) float f32x4;

#define L2A     (-0.014499569695115089f)   // log2(0.99)
#define RSQRTD  (0.03608439182435161f)     // 1/sqrt(768)

__device__ __forceinline__ unsigned short f2bf(float x) {
  union { float f; unsigned u; } v; v.f = x;
  unsigned r = v.u + 0x7FFFu + ((v.u >> 16) & 1u);
  return (unsigned short)(r >> 16);
}

__device__ __forceinline__ void gload16(const void* g, void* l) {
  __builtin_amdgcn_global_load_lds(
      (const __attribute__((address_space(1))) void*)g,
      (__attribute__((address_space(3))) void*)l, 16, 0, 0);
}

// stage a 128x64 bf16 tile (row-major, leading dim ld) into lds[128][64] linear.
// gsrc is the PER-LANE source: base + srow*ld + scol, srow=wid*8+(lane>>3), scol=(lane&7)*8
__device__ __forceinline__ void stage128x64(const unsigned short* gsrc, size_t ld,
                                            unsigned short* lds, int wid) {
#pragma unroll
  for (int i = 0; i < 4; ++i)
    gload16(gsrc + (size_t)i * 32 * ld, lds + i * 2048 + wid * 512);
}

// 16 MFMA x 2 k-halves on the staged tiles
__device__ __forceinline__ void mfma_tile(const short* lsA, const short* lsB,
                                          int wr, int wc, int lr, int lg,
                                          f32x4 acc[4][4]) {
#pragma unroll
  for (int ks = 0; ks < 64; ks += 32) {
    bf16x8 af[4], bfr[4];
#pragma unroll
    for (int m = 0; m < 4; ++m)
      af[m] = *(const bf16x8*)&lsA[(wr * 64 + m * 16 + lr) * 64 + ks + lg * 8];
#pragma unroll
    for (int n = 0; n < 4; ++n)
      bfr[n] = *(const bf16x8*)&lsB[(wc * 64 + n * 16 + lr) * 64 + ks + lg * 8];
#pragma unroll
    for (int m = 0; m < 4; ++m)
#pragma unroll
      for (int n = 0; n < 4; ++n)
        acc[m][n] = __builtin_amdgcn_mfma_f32_16x16x32_bf16(af[m], bfr[n], acc[m][n], 0, 0, 0);
  }
}

// ---------------- x f32 -> bf16 (one 8192-row half), vectorized
__global__ void convert_x(const float* __restrict__ x, unsigned short* __restrict__ xb) {
  size_t i = ((size_t)blockIdx.x * 256 + threadIdx.x) * 8;
  float4 f0 = *(const float4*)(x + i);
  float4 f1 = *(const float4*)(x + i + 4);
  bf16x8 v;
  v[0] = (short)f2bf(f0.x); v[1] = (short)f2bf(f0.y);
  v[2] = (short)f2bf(f0.z); v[3] = (short)f2bf(f0.w);
  v[4] = (short)f2bf(f1.x); v[5] = (short)f2bf(f1.y);
  v[6] = (short)f2bf(f1.z); v[7] = (short)f2bf(f1.w);
  *(bf16x8*)(xb + i) = v;
}

// ---------------- W transpose+convert: W[768][2304] f32 -> Wt[2304][768] bf16
__global__ void transpose_w(const float* __restrict__ W, unsigned short* __restrict__ Wt) {
  __shared__ float tile[64][65];
  int n0 = (blockIdx.x % 36) * 64;
  int k0 = (blockIdx.x / 36) * 64;
  int tx = threadIdx.x & 63, ty = threadIdx.x >> 6;   // 256 thr: 64 x 4
#pragma unroll
  for (int p = 0; p < 16; ++p) {
    int k = ty + p * 4;
    tile[k][tx] = W[(size_t)(k0 + k) * ND3 + n0 + tx];
  }
  __syncthreads();
#pragma unroll
  for (int p = 0; p < 16; ++p) {
    int n = ty + p * 4;
    Wt[(size_t)(n0 + n) * DIM + k0 + tx] = f2bf(tile[tx][n]);
  }
}

// ---------------- QKV GEMM (one half: 8192 rows): xb @ Wt^T + b -> Q',K',Vt
__global__ void __launch_bounds__(256) qkv_gemm(
    const unsigned short* __restrict__ xb, const unsigned short* __restrict__ Wt,
    const float* __restrict__ bias,
    unsigned short* __restrict__ Qs, unsigned short* __restrict__ Ks,
    unsigned short* __restrict__ Vt, int m_base) {
  __shared__ short lsA[128 * 64];
  __shared__ short lsB[128 * 64];
  int nt = blockIdx.x % 18, mt = blockIdx.x / 18;
  int m0 = mt * 128, n0 = nt * 128;
  int tid = threadIdx.x;
  int lane = tid & 63, wid = tid >> 6;
  int wr = wid >> 1, wc = wid & 1;
  int lr = lane & 15, lg = lane >> 4;
  int srow = wid * 8 + (lane >> 3), scol = (lane & 7) * 8;

  const unsigned short* ga = xb + (size_t)(m0 + srow) * DIM + scol;
  const unsigned short* gb = Wt + (size_t)(n0 + srow) * DIM + scol;

  f32x4 acc[4][4] = {};

  for (int k0 = 0; k0 < DIM; k0 += 64) {
    stage128x64(ga + k0, DIM, (unsigned short*)lsA, wid);
    stage128x64(gb + k0, DIM, (unsigned short*)lsB, wid);
    __syncthreads();
    mfma_tile(lsA, lsB, wr, wc, lr, lg, acc);
    __syncthreads();
  }

  // epilogue: whole block is one of Q / K / V (128 | DIM boundaries)
  float bia[4];
#pragma unroll
  for (int n = 0; n < 4; ++n) bia[n] = bias[n0 + wc * 64 + n * 16 + lr];

  if (nt < 6) {            // Q: scale by alpha^s / sqrt(d)
#pragma unroll
    for (int m = 0; m < 4; ++m)
#pragma unroll
      for (int r = 0; r < 4; ++r) {
        int mg = m_base + m0 + wr * 64 + m * 16 + lg * 4 + r;
        int b = mg >> 10, s = mg & 1023;
        float sc = exp2f((float)s * L2A) * RSQRTD;
        unsigned short* dst = Qs + ((size_t)b * SEQ + s) * DIM + n0 + wc * 64 + lr;
#pragma unroll
        for (int n = 0; n < 4; ++n)
          dst[n * 16] = f2bf((acc[m][n][r] + bia[n]) * sc);
      }
  } else if (nt < 12) {    // K: scale by alpha^(-s)
#pragma unroll
    for (int m = 0; m < 4; ++m)
#pragma unroll
      for (int r = 0; r < 4; ++r) {
        int mg = m_base + m0 + wr * 64 + m * 16 + lg * 4 + r;
        int b = mg >> 10, s = mg & 1023;
        float sc = exp2f(-(float)s * L2A);
        unsigned short* dst = Ks + ((size_t)b * SEQ + s) * DIM + (n0 - DIM) + wc * 64 + lr;
#pragma unroll
        for (int n = 0; n < 4; ++n)
          dst[n * 16] = f2bf((acc[m][n][r] + bia[n]) * sc);
      }
  } else {                 // V: transpose to Vt[b][d][s]
#pragma unroll
    for (int m = 0; m < 4; ++m)
#pragma unroll
      for (int r = 0; r < 4; ++r) {
        int mg = m_base + m0 + wr * 64 + m * 16 + lg * 4 + r;
        int b = mg >> 10, s = mg & 1023;
        int d = (n0 - 2 * DIM) + wc * 64 + lr;
        unsigned short* dst = Vt + ((size_t)b * DIM + d) * SEQ + s;
#pragma unroll
        for (int n = 0; n < 4; ++n)
          dst[(size_t)n * 16 * SEQ] = f2bf(acc[m][n][r] + bia[n]);
      }
  }
}

// ---------------- scores: Sm[bl][i][j] = tril(Q'[b] @ K'[b]^T), bf16
__global__ void __launch_bounds__(256) score_gemm(
    const unsigned short* __restrict__ Qs, const unsigned short* __restrict__ Ks,
    unsigned short* __restrict__ Sm, int b_base) {
  __shared__ short lsA[128 * 64];
  __shared__ short lsB[128 * 64];
  int t = blockIdx.x % 36;
  int bl = blockIdx.x / 36;
  int b = b_base + bl;
  int it = 0;
  while (t >= it + 1) { t -= it + 1; it++; }
  int jt = t;
  int m0 = it * 128, n0 = jt * 128;
  const unsigned short* A  = Qs + (size_t)b * SEQ * DIM;
  const unsigned short* Bt = Ks + (size_t)b * SEQ * DIM;
  unsigned short* Smp = Sm + (size_t)bl * SEQ * SEQ;

  int tid = threadIdx.x;
  int lane = tid & 63, wid = tid >> 6;
  int wr = wid >> 1, wc = wid & 1;
  int lr = lane & 15, lg = lane >> 4;
  int srow = wid * 8 + (lane >> 3), scol = (lane & 7) * 8;

  const unsigned short* ga = A  + (size_t)(m0 + srow) * DIM + scol;
  const unsigned short* gb = Bt + (size_t)(n0 + srow) * DIM + scol;

  f32x4 acc[4][4] = {};

  for (int k0 = 0; k0 < DIM; k0 += 64) {
    stage128x64(ga + k0, DIM, (unsigned short*)lsA, wid);
    stage128x64(gb + k0, DIM, (unsigned short*)lsB, wid);
    __syncthreads();
    mfma_tile(lsA, lsB, wr, wc, lr, lg, acc);
    __syncthreads();
  }

#pragma unroll
  for (int m = 0; m < 4; ++m)
#pragma unroll
    for (int n = 0; n < 4; ++n) {
      int j = n0 + wc * 64 + n * 16 + lr;
#pragma unroll
      for (int r = 0; r < 4; ++r) {
        int i = m0 + wr * 64 + m * 16 + lg * 4 + r;
        float v = acc[m][n][r];
        if (j > i) v = 0.0f;   // causal mask (bites only on diagonal tiles)
        Smp[(size_t)i * SEQ + j] = f2bf(v);
      }
    }
}

// ---------------- PV: out[b][i][d] = Sm[bl] @ V[b];  B-operand = Vt[b] [d][s]
__global__ void __launch_bounds__(256) pv_gemm(
    const unsigned short* __restrict__ Sm, const unsigned short* __restrict__ Vt,
    float* __restrict__ out, int b_base) {
  __shared__ short lsA[128 * 64];
  __shared__ short lsB[128 * 64];
  // heavy tiles (large it => large kmax) scheduled first
  int it = 7 - blockIdx.x / 48;
  int rem = blockIdx.x % 48;
  int nt = rem / 8, bl = rem % 8;
  int b = b_base + bl;
  int m0 = it * 128, n0 = nt * 128;
  const unsigned short* A  = Sm + (size_t)bl * SEQ * SEQ;   // ld = 1024
  const unsigned short* Bt = Vt + (size_t)b * DIM * SEQ;    // ld = 1024
  int kmax = (it + 1) * 128;

  int tid = threadIdx.x;
  int lane = tid & 63, wid = tid >> 6;
  int wr = wid >> 1, wc = wid & 1;
  int lr = lane & 15, lg = lane >> 4;
  int srow = wid * 8 + (lane >> 3), scol = (lane & 7) * 8;

  const unsigned short* ga = A  + (size_t)(m0 + srow) * SEQ + scol;
  const unsigned short* gb = Bt + (size_t)(n0 + srow) * SEQ + scol;

  f32x4 acc[4][4] = {};

  for (int k0 = 0; k0 < kmax; k0 += 64) {
    stage128x64(ga + k0, SEQ, (unsigned short*)lsA, wid);
    stage128x64(gb + k0, SEQ, (unsigned short*)lsB, wid);
    __syncthreads();
    mfma_tile(lsA, lsB, wr, wc, lr, lg, acc);
    __syncthreads();
  }

#pragma unroll
  for (int m = 0; m < 4; ++m)
#pragma unroll
    for (int n = 0; n < 4; ++n) {
      int ng = n0 + wc * 64 + n * 16 + lr;
#pragma unroll
      for (int r = 0; r < 4; ++r) {
        int mg = m0 + wr * 64 + m * 16 + lg * 4 + r;
        out[((size_t)b * SEQ + mg) * DIM + ng] = acc[m][n][r];
      }
    }
}

extern "C" void kernel_launch(void* const* d_in, const int* in_sizes, int n_in,
                              void* d_out, int out_size, void* d_ws, size_t ws_size,
                              hipStream_t stream) {
  const float* x    = (const float*)d_in[0];
  const float* W    = (const float*)d_in[1];
  const float* bias = (const float*)d_in[2];
  float* out = (float*)d_out;

  char* ws = (char*)d_ws;
  // ws layout (95,813,632 B total — identical budget to round 0):
  //   Wt : 3,538,944
  //   Qs : 25,165,824
  //   Ks : 25,165,824
  //   Vt : 25,165,824
  //   R  : 16,777,216  (xb half [12.6MB] during qkv; Sm [16.8MB] during score/pv)
  unsigned short* Wt = (unsigned short*)(ws);
  unsigned short* Qs = (unsigned short*)(ws + 3538944);
  unsigned short* Ks = (unsigned short*)(ws + 3538944 + 25165824);
  unsigned short* Vt = (unsigned short*)(ws + 3538944 + 2 * 25165824);
  unsigned short* R  = (unsigned short*)(ws + 3538944 + 3 * 25165824);
  unsigned short* xb = R;
  unsigned short* Sm = R;

  transpose_w<<<36 * 12, 256, 0, stream>>>(W, Wt);
  for (int h = 0; h < 2; ++h) {
    convert_x<<<3072, 256, 0, stream>>>(x + (size_t)h * 8192 * DIM, xb);
    qkv_gemm<<<64 * 18, 256, 0, stream>>>(xb, Wt, bias, Qs, Ks, Vt, h * 8192);
  }
  for (int g = 0; g < 2; ++g) {
    score_gemm<<<GROUP * 36, 256, 0, stream>>>(Qs, Ks, Sm, g * GROUP);
    pv_gemm<<<GROUP * 48, 256, 0, stream>>>(Sm, Vt, out, g * GROUP);
  }
}

// Round 3
// 213.983 us; speedup vs baseline: 1.2085x; 1.2085x over previous
//
#include <hip/hip_runtime.h>
#include <hip/hip_bf16.h>

// Retention: out = (tril(alpha^(i-j)) * (QK^T/sqrt(d))) @ V, qkv = x@W + b
// Decay folded into operands: Q' = q*alpha^i/sqrt(d), K' = k*alpha^(-j)
// qkv: 256^2 8-phase schedule (T2 swizzle + T3/T4 counted staging + T5 setprio).
// score/pv: m97-style 128^2 (unchanged this round).

#define SEQ   1024
#define DIM   768
#define ND3   2304
#define GROUP 8

typedef __attribute__((ext_vector_type(8))) short bf16x8;
typedef __attribute__((ext_vector_type(4))) float f32x4;

#define L2A     (-0.014499569695115089f)   // log2(0.99)
#define RSQRTD  (0.03608439182435161f)     // 1/sqrt(768)

__device__ __forceinline__ unsigned short f2bf(float x) {
  union { float f; unsigned u; } v; v.f = x;
  unsigned r = v.u + 0x7FFFu + ((v.u >> 16) & 1u);
  return (unsigned short)(r >> 16);
}

__device__ __forceinline__ void gload16(const void* g, void* l) {
  __builtin_amdgcn_global_load_lds(
      (const __attribute__((address_space(1))) void*)g,
      (__attribute__((address_space(3))) void*)l, 16, 0, 0);
}

// ---------------- x f32 -> bf16 (full 16384 rows), vectorized
__global__ void convert_x(const float* __restrict__ x, unsigned short* __restrict__ xb) {
  size_t i = ((size_t)blockIdx.x * 256 + threadIdx.x) * 8;
  float4 f0 = *(const float4*)(x + i);
  float4 f1 = *(const float4*)(x + i + 4);
  bf16x8 v;
  v[0] = (short)f2bf(f0.x); v[1] = (short)f2bf(f0.y);
  v[2] = (short)f2bf(f0.z); v[3] = (short)f2bf(f0.w);
  v[4] = (short)f2bf(f1.x); v[5] = (short)f2bf(f1.y);
  v[6] = (short)f2bf(f1.z); v[7] = (short)f2bf(f1.w);
  *(bf16x8*)(xb + i) = v;
}

// ---------------- W transpose+convert: W[768][2304] f32 -> Wt[2304][768] bf16
__global__ void transpose_w(const float* __restrict__ W, unsigned short* __restrict__ Wt) {
  __shared__ float tile[64][65];
  int n0 = (blockIdx.x % 36) * 64;
  int k0 = (blockIdx.x / 36) * 64;
  int tx = threadIdx.x & 63, ty = threadIdx.x >> 6;
#pragma unroll
  for (int p = 0; p < 16; ++p) {
    int k = ty + p * 4;
    tile[k][tx] = W[(size_t)(k0 + k) * ND3 + n0 + tx];
  }
  __syncthreads();
#pragma unroll
  for (int p = 0; p < 16; ++p) {
    int n = ty + p * 4;
    Wt[(size_t)(n0 + n) * DIM + k0 + tx] = f2bf(tile[tx][n]);
  }
}

// ---------------- QKV GEMM: 256x256 tile, BK=64, 8 waves (2M x 4N), 8-phase.
// Per wave: 128x64 output = acc[8][4]. LDS 128KB: 2 K-tile buffers per operand.
// Swizzle: element-col ^= (row&7)*8 on both gload-source and ds_read.
// Buffer rotation: tile 2t+1 (par1) staged phases 0-3; tile 2t+2 (par0) phases 4-7.
// Gates (vmcnt(0)+barrier) at end of phases 3 and 7 are exact (only the needed
// tile's loads are outstanding there) -> correctness independent of latency.

#define STAGE(tk, s) do {                                                     \
    if ((tk) < 12) {                                                          \
      int u_ = (s) & 1;                                                       \
      const unsigned short* gsrc_ = ((s) < 2 ? gA : gB);                      \
      short* ldst_ = ((s) < 2 ? &lsA[(tk) & 1][0] : &lsB[(tk) & 1][0]);       \
      _Pragma("unroll")                                                       \
      for (int i_ = 0; i_ < 2; ++i_) {                                        \
        int c_ = wid + i_ * 8;                                                \
        int row_ = u_ * 128 + c_ * 8 + l8;                                    \
        gload16(gsrc_ + (size_t)row_ * DIM + (tk) * 64,                       \
                ldst_ + u_ * 8192 + c_ * 512);                                \
      }                                                                       \
    }                                                                         \
  } while (0)

#define PHASE(par, kh, mh, stk, sts, gate) do {                               \
    STAGE(stk, sts);                                                          \
    bf16x8 aF_[4], bF_[4];                                                    \
    _Pragma("unroll")                                                         \
    for (int f_ = 0; f_ < 4; ++f_) {                                          \
      int ra_ = wm * 128 + (mh) * 64 + f_ * 16 + lr;                          \
      int ke_ = (kh) * 32 + lg * 8;                                           \
      aF_[f_] = *(const bf16x8*)&lsA[par][ra_ * 64 + (ke_ ^ ((ra_ & 7) * 8))];\
      int rb_ = wn * 64 + f_ * 16 + lr;                                       \
      bF_[f_] = *(const bf16x8*)&lsB[par][rb_ * 64 + (ke_ ^ ((rb_ & 7) * 8))];\
    }                                                                         \
    __builtin_amdgcn_s_barrier();                                             \
    __builtin_amdgcn_s_setprio(1);                                            \
    _Pragma("unroll")                                                         \
    for (int f_ = 0; f_ < 4; ++f_)                                            \
      _Pragma("unroll")                                                       \
      for (int n_ = 0; n_ < 4; ++n_)                                          \
        acc[(mh) * 4 + f_][n_] = __builtin_amdgcn_mfma_f32_16x16x32_bf16(     \
            aF_[f_], bF_[n_], acc[(mh) * 4 + f_][n_], 0, 0, 0);               \
    __builtin_amdgcn_s_setprio(0);                                            \
    if (gate) { asm volatile("s_waitcnt vmcnt(0)" ::: "memory"); }            \
    __builtin_amdgcn_s_barrier();                                             \
    asm volatile("" ::: "memory");                                            \
  } while (0)

__global__ void __launch_bounds__(512, 2) qkv_gemm8(
    const unsigned short* __restrict__ xb, const unsigned short* __restrict__ Wt,
    const float* __restrict__ bias,
    unsigned short* __restrict__ Qs, unsigned short* __restrict__ Ks,
    unsigned short* __restrict__ Vt) {
  __shared__ short lsA[2][16384];   // [par][256 rows][64 cols]
  __shared__ short lsB[2][16384];

  // bijective XCD swizzle: grid 576 = 8 xcd * 72 chunks
  int bid0 = blockIdx.x;
  int bid = (bid0 & 7) * 72 + (bid0 >> 3);
  int mt = bid / 9, nt = bid % 9;
  int m0 = mt * 256, n0 = nt * 256;

  int tid = threadIdx.x;
  int lane = tid & 63, wid = tid >> 6;
  int wm = wid >> 2, wn = wid & 3;          // 2 x 4 waves
  int lr = lane & 15, lg = lane >> 4;
  int l8 = lane >> 3;                        // row-in-chunk
  int swc = ((lane & 7) ^ l8) * 8;           // pre-swizzled global col (elements)

  const unsigned short* gA = xb + (size_t)m0 * DIM + swc;
  const unsigned short* gB = Wt + (size_t)n0 * DIM + swc;

  f32x4 acc[8][4] = {};

  // prologue: stage tile 0 (par 0), gate
  STAGE(0, 0); STAGE(0, 1); STAGE(0, 2); STAGE(0, 3);
  asm volatile("s_waitcnt vmcnt(0)" ::: "memory");
  __builtin_amdgcn_s_barrier();
  asm volatile("" ::: "memory");

  for (int t = 0; t < 6; ++t) {
    int k1 = 2 * t + 1;
    int k2 = 2 * t + 2;
    // phases 0-3: compute tile 2t (par0), stage tile 2t+1 (par1)
    PHASE(0, 0, 0, k1, 0, false);
    PHASE(0, 1, 0, k1, 1, false);
    PHASE(0, 0, 1, k1, 2, false);
    PHASE(0, 1, 1, k1, 3, true);    // gate: tile 2t+1 ready
    // phases 4-7: compute tile 2t+1 (par1), stage tile 2t+2 (par0)
    PHASE(1, 0, 0, k2, 0, false);
    PHASE(1, 1, 0, k2, 1, false);
    PHASE(1, 0, 1, k2, 2, false);
    PHASE(1, 1, 1, k2, 3, true);    // gate: tile 2t+2 ready
  }

  // epilogue: bias + decay scaling; nt<3 -> Q, nt<6 -> K, else V (exact 256-splits)
  float bia[4];
#pragma unroll
  for (int n = 0; n < 4; ++n) bia[n] = bias[n0 + wn * 64 + n * 16 + lr];

  if (nt < 3) {          // Q: * alpha^s / sqrt(d)
#pragma unroll
    for (int ai = 0; ai < 8; ++ai)
#pragma unroll
      for (int r = 0; r < 4; ++r) {
        int mg = m0 + wm * 128 + ai * 16 + lg * 4 + r;
        int b = mg >> 10, s = mg & 1023;
        float sc = exp2f((float)s * L2A) * RSQRTD;
        unsigned short* dst = Qs + ((size_t)b * SEQ + s) * DIM + n0 + wn * 64 + lr;
#pragma unroll
        for (int n = 0; n < 4; ++n)
          dst[n * 16] = f2bf((acc[ai][n][r] + bia[n]) * sc);
      }
  } else if (nt < 6) {   // K: * alpha^(-s)
#pragma unroll
    for (int ai = 0; ai < 8; ++ai)
#pragma unroll
      for (int r = 0; r < 4; ++r) {
        int mg = m0 + wm * 128 + ai * 16 + lg * 4 + r;
        int b = mg >> 10, s = mg & 1023;
        float sc = exp2f(-(float)s * L2A);
        unsigned short* dst = Ks + ((size_t)b * SEQ + s) * DIM + (n0 - DIM) + wn * 64 + lr;
#pragma unroll
        for (int n = 0; n < 4; ++n)
          dst[n * 16] = f2bf((acc[ai][n][r] + bia[n]) * sc);
      }
  } else {               // V: transpose to Vt[b][d][s]
#pragma unroll
    for (int ai = 0; ai < 8; ++ai)
#pragma unroll
      for (int r = 0; r < 4; ++r) {
        int mg = m0 + wm * 128 + ai * 16 + lg * 4 + r;
        int b = mg >> 10, s = mg & 1023;
        int d = (n0 - 2 * DIM) + wn * 64 + lr;
        unsigned short* dst = Vt + ((size_t)b * DIM + d) * SEQ + s;
#pragma unroll
        for (int n = 0; n < 4; ++n)
          dst[(size_t)n * 16 * SEQ] = f2bf(acc[ai][n][r] + bia[n]);
      }
  }
}

// ---------------- shared 128^2 helpers for score/pv (unchanged structure)
__device__ __forceinline__ void stage128x64(const unsigned short* gsrc, size_t ld,
                                            unsigned short* lds, int wid) {
#pragma unroll
  for (int i = 0; i < 4; ++i)
    gload16(gsrc + (size_t)i * 32 * ld, lds + i * 2048 + wid * 512);
}

__device__ __forceinline__ void mfma_tile(const short* lsA, const short* lsB,
                                          int wr, int wc, int lr, int lg,
                                          f32x4 acc[4][4]) {
#pragma unroll
  for (int ks = 0; ks < 64; ks += 32) {
    bf16x8 af[4], bfr[4];
#pragma unroll
    for (int m = 0; m < 4; ++m)
      af[m] = *(const bf16x8*)&lsA[(wr * 64 + m * 16 + lr) * 64 + ks + lg * 8];
#pragma unroll
    for (int n = 0; n < 4; ++n)
      bfr[n] = *(const bf16x8*)&lsB[(wc * 64 + n * 16 + lr) * 64 + ks + lg * 8];
#pragma unroll
    for (int m = 0; m < 4; ++m)
#pragma unroll
      for (int n = 0; n < 4; ++n)
        acc[m][n] = __builtin_amdgcn_mfma_f32_16x16x32_bf16(af[m], bfr[n], acc[m][n], 0, 0, 0);
  }
}

// ---------------- scores: Sm[bl][i][j] = tril(Q'[b] @ K'[b]^T), bf16
__global__ void __launch_bounds__(256) score_gemm(
    const unsigned short* __restrict__ Qs, const unsigned short* __restrict__ Ks,
    unsigned short* __restrict__ Sm, int b_base) {
  __shared__ short lsA[128 * 64];
  __shared__ short lsB[128 * 64];
  int t = blockIdx.x % 36;
  int bl = blockIdx.x / 36;
  int b = b_base + bl;
  int it = 0;
  while (t >= it + 1) { t -= it + 1; it++; }
  int jt = t;
  int m0 = it * 128, n0 = jt * 128;
  const unsigned short* A  = Qs + (size_t)b * SEQ * DIM;
  const unsigned short* Bt = Ks + (size_t)b * SEQ * DIM;
  unsigned short* Smp = Sm + (size_t)bl * SEQ * SEQ;

  int tid = threadIdx.x;
  int lane = tid & 63, wid = tid >> 6;
  int wr = wid >> 1, wc = wid & 1;
  int lr = lane & 15, lg = lane >> 4;
  int srow = wid * 8 + (lane >> 3), scol = (lane & 7) * 8;

  const unsigned short* ga = A  + (size_t)(m0 + srow) * DIM + scol;
  const unsigned short* gb = Bt + (size_t)(n0 + srow) * DIM + scol;

  f32x4 acc[4][4] = {};

  for (int k0 = 0; k0 < DIM; k0 += 64) {
    stage128x64(ga + k0, DIM, (unsigned short*)lsA, wid);
    stage128x64(gb + k0, DIM, (unsigned short*)lsB, wid);
    __syncthreads();
    mfma_tile(lsA, lsB, wr, wc, lr, lg, acc);
    __syncthreads();
  }

#pragma unroll
  for (int m = 0; m < 4; ++m)
#pragma unroll
    for (int n = 0; n < 4; ++n) {
      int j = n0 + wc * 64 + n * 16 + lr;
#pragma unroll
      for (int r = 0; r < 4; ++r) {
        int i = m0 + wr * 64 + m * 16 + lg * 4 + r;
        float v = acc[m][n][r];
        if (j > i) v = 0.0f;
        Smp[(size_t)i * SEQ + j] = f2bf(v);
      }
    }
}

// ---------------- PV: out[b][i][d] = Sm[bl] @ V[b];  B-operand = Vt[b] [d][s]
__global__ void __launch_bounds__(256) pv_gemm(
    const unsigned short* __restrict__ Sm, const unsigned short* __restrict__ Vt,
    float* __restrict__ out, int b_base) {
  __shared__ short lsA[128 * 64];
  __shared__ short lsB[128 * 64];
  int it = 7 - blockIdx.x / 48;        // heavy tiles first
  int rem = blockIdx.x % 48;
  int nt = rem / 8, bl = rem % 8;
  int b = b_base + bl;
  int m0 = it * 128, n0 = nt * 128;
  const unsigned short* A  = Sm + (size_t)bl * SEQ * SEQ;
  const unsigned short* Bt = Vt + (size_t)b * DIM * SEQ;
  int kmax = (it + 1) * 128;

  int tid = threadIdx.x;
  int lane = tid & 63, wid = tid >> 6;
  int wr = wid >> 1, wc = wid & 1;
  int lr = lane & 15, lg = lane >> 4;
  int srow = wid * 8 + (lane >> 3), scol = (lane & 7) * 8;

  const unsigned short* ga = A  + (size_t)(m0 + srow) * SEQ + scol;
  const unsigned short* gb = Bt + (size_t)(n0 + srow) * SEQ + scol;

  f32x4 acc[4][4] = {};

  for (int k0 = 0; k0 < kmax; k0 += 64) {
    stage128x64(ga + k0, SEQ, (unsigned short*)lsA, wid);
    stage128x64(gb + k0, SEQ, (unsigned short*)lsB, wid);
    __syncthreads();
    mfma_tile(lsA, lsB, wr, wc, lr, lg, acc);
    __syncthreads();
  }

#pragma unroll
  for (int m = 0; m < 4; ++m)
#pragma unroll
    for (int n = 0; n < 4; ++n) {
      int ng = n0 + wc * 64 + n * 16 + lr;
#pragma unroll
      for (int r = 0; r < 4; ++r) {
        int mg = m0 + wr * 64 + m * 16 + lg * 4 + r;
        out[((size_t)b * SEQ + mg) * DIM + ng] = acc[m][n][r];
      }
    }
}

extern "C" void kernel_launch(void* const* d_in, const int* in_sizes, int n_in,
                              void* d_out, int out_size, void* d_ws, size_t ws_size,
                              hipStream_t stream) {
  const float* x    = (const float*)d_in[0];
  const float* W    = (const float*)d_in[1];
  const float* bias = (const float*)d_in[2];
  float* out = (float*)d_out;

  char* ws = (char*)d_ws;
  // ws layout (95.8 MB, same budget as proven):
  //   Wt : 3,538,944 | Qs/Ks/Vt : 25,165,824 each | Sm : 16,777,216
  unsigned short* Wt = (unsigned short*)(ws);
  unsigned short* Qs = (unsigned short*)(ws + 3538944);
  unsigned short* Ks = (unsigned short*)(ws + 3538944 + 25165824);
  unsigned short* Vt = (unsigned short*)(ws + 3538944 + 2 * 25165824);
  unsigned short* Sm = (unsigned short*)(ws + 3538944 + 3 * 25165824);
  // full bf16 x lives in d_out (50.3MB >= 25.2MB); qkv reads it before pv writes out.
  unsigned short* xb = (unsigned short*)d_out;

  transpose_w<<<36 * 12, 256, 0, stream>>>(W, Wt);
  convert_x<<<6144, 256, 0, stream>>>(x, xb);
  qkv_gemm8<<<576, 512, 0, stream>>>(xb, Wt, bias, Qs, Ks, Vt);
  for (int g = 0; g < 2; ++g) {
    score_gemm<<<GROUP * 36, 256, 0, stream>>>(Qs, Ks, Sm, g * GROUP);
    pv_gemm<<<GROUP * 48, 256, 0, stream>>>(Sm, Vt, out, g * GROUP);
  }
}

// Round 4
// 206.615 us; speedup vs baseline: 1.2516x; 1.0357x over previous
//
#include <hip/hip_runtime.h>
#include <hip/hip_bf16.h>

// Retention: out = (tril(alpha^(i-j)) * (QK^T/sqrt(d))) @ V, qkv = x@W + b
// Decay folded into operands: Q' = q*alpha^i/sqrt(d), K' = k*alpha^(-j)
// All GEMMs: 128x256 tile, 8 waves (64x64/wave), BK=32 double-buffered (48KB LDS,
// 2 blocks/CU), counted vmcnt(3) gate (waited tile staged one full K-tile earlier),
// 2 barriers/K-tile, XOR slot swizzle on src+read (LDS dest linear).

#define SEQ   1024
#define DIM   768
#define ND3   2304
#define GROUP 8

typedef __attribute__((ext_vector_type(8))) short bf16x8;
typedef __attribute__((ext_vector_type(4))) float f32x4;

#define L2A     (-0.014499569695115089f)   // log2(0.99)
#define RSQRTD  (0.03608439182435161f)     // 1/sqrt(768)

#define SWZ(R) ((((R) >> 2) ^ (R)) & 3)

__device__ __forceinline__ unsigned short f2bf(float x) {
  union { float f; unsigned u; } v; v.f = x;
  unsigned r = v.u + 0x7FFFu + ((v.u >> 16) & 1u);
  return (unsigned short)(r >> 16);
}

__device__ __forceinline__ void gload16(const void* g, void* l) {
  __builtin_amdgcn_global_load_lds(
      (const __attribute__((address_space(1))) void*)g,
      (__attribute__((address_space(3))) void*)l, 16, 0, 0);
}

// ---- shared GEMM core: C[128x256] += A[128xK] * B[256xK]^T, K = nt*32.
// gA: per-lane A src (pre-swizzled col, row m0 + wid*16 + (lane>>2))
// gB0/gB1: per-lane B src chunks (rows wid*16.., (wid+8)*16..)
// lsA: [2][128*32] shorts, lsB: [2][256*32] shorts.
__device__ __forceinline__ void gemm_core(
    const unsigned short* gA, const unsigned short* gB0, const unsigned short* gB1,
    size_t ldA, size_t ldB, short* lsA, short* lsB, int nt,
    int wid, int lane, f32x4 acc[4][4]) {
  int wm = wid >> 2, wn = wid & 3;
  int lr = lane & 15, lg = lane >> 4;

#define STAGE32(t, par) do {                                                  \
    gload16(gA + (size_t)(t) * 32, lsA + (par) * 4096 + wid * 512);           \
    gload16(gB0 + (size_t)(t) * 32, lsB + (par) * 8192 + wid * 512);          \
    gload16(gB1 + (size_t)(t) * 32, lsB + (par) * 8192 + (wid + 8) * 512);    \
  } while (0)

  STAGE32(0, 0);
  STAGE32(1, 1);
  asm volatile("s_waitcnt vmcnt(3)" ::: "memory");
  __builtin_amdgcn_s_barrier();

  for (int t = 0; t < nt; ++t) {
    int par = t & 1;
    bf16x8 aF[4], bF[4];
#pragma unroll
    for (int f = 0; f < 4; ++f) {
      int Ra = wm * 64 + f * 16 + lr;
      aF[f] = *(const bf16x8*)&lsA[par * 4096 + Ra * 32 + ((lg ^ SWZ(Ra)) << 3)];
    }
#pragma unroll
    for (int n = 0; n < 4; ++n) {
      int Rb = wn * 64 + n * 16 + lr;
      bF[n] = *(const bf16x8*)&lsB[par * 8192 + Rb * 32 + ((lg ^ SWZ(Rb)) << 3)];
    }
    __builtin_amdgcn_s_setprio(1);
#pragma unroll
    for (int f = 0; f < 4; ++f)
#pragma unroll
      for (int n = 0; n < 4; ++n)
        acc[f][n] = __builtin_amdgcn_mfma_f32_16x16x32_bf16(aF[f], bF[n], acc[f][n], 0, 0, 0);
    __builtin_amdgcn_s_setprio(0);

    if (t == nt - 1) break;
    __builtin_amdgcn_s_barrier();          // all reads of tile t done
    if (t + 2 < nt) {
      STAGE32(t + 2, par);                 // refill the buffer tile t used
      asm volatile("s_waitcnt vmcnt(3)" ::: "memory");   // tile t+1 ready (counted)
    } else {
      asm volatile("s_waitcnt vmcnt(0)" ::: "memory");   // drain last tile
    }
    __builtin_amdgcn_s_barrier();          // all waves gated
  }
#undef STAGE32
}

// ---------------- x f32 -> bf16, vectorized
__global__ void convert_x(const float* __restrict__ x, unsigned short* __restrict__ xb) {
  size_t i = ((size_t)blockIdx.x * 256 + threadIdx.x) * 8;
  float4 f0 = *(const float4*)(x + i);
  float4 f1 = *(const float4*)(x + i + 4);
  bf16x8 v;
  v[0] = (short)f2bf(f0.x); v[1] = (short)f2bf(f0.y);
  v[2] = (short)f2bf(f0.z); v[3] = (short)f2bf(f0.w);
  v[4] = (short)f2bf(f1.x); v[5] = (short)f2bf(f1.y);
  v[6] = (short)f2bf(f1.z); v[7] = (short)f2bf(f1.w);
  *(bf16x8*)(xb + i) = v;
}

// ---------------- W transpose+convert: W[768][2304] f32 -> Wt[2304][768] bf16
__global__ void transpose_w(const float* __restrict__ W, unsigned short* __restrict__ Wt) {
  __shared__ float tile[64][65];
  int n0 = (blockIdx.x % 36) * 64;
  int k0 = (blockIdx.x / 36) * 64;
  int tx = threadIdx.x & 63, ty = threadIdx.x >> 6;
#pragma unroll
  for (int p = 0; p < 16; ++p) {
    int k = ty + p * 4;
    tile[k][tx] = W[(size_t)(k0 + k) * ND3 + n0 + tx];
  }
  __syncthreads();
#pragma unroll
  for (int p = 0; p < 16; ++p) {
    int n = ty + p * 4;
    Wt[(size_t)(n0 + n) * DIM + k0 + tx] = f2bf(tile[tx][n]);
  }
}

// ---------------- QKV: xb[16384][768] @ Wt^T -> Q',K',Vt. grid 1152 = 128mt x 9nt
__global__ void __launch_bounds__(512, 4) qkv_g(
    const unsigned short* __restrict__ xb, const unsigned short* __restrict__ Wt,
    const float* __restrict__ bias,
    unsigned short* __restrict__ Qs, unsigned short* __restrict__ Ks,
    unsigned short* __restrict__ Vt) {
  __shared__ short lsA[2 * 4096];
  __shared__ short lsB[2 * 8192];
  int bid = (blockIdx.x & 7) * 144 + (blockIdx.x >> 3);   // bijective XCD swizzle
  int mt = bid / 9, ntb = bid % 9;
  int m0 = mt * 128, n0 = ntb * 256;

  int tid = threadIdx.x, lane = tid & 63, wid = tid >> 6;
  int wm = wid >> 2, wn = wid & 3;
  int lr = lane & 15, lg = lane >> 4;

  int rA = wid * 16 + (lane >> 2);
  int cs = ((lane & 3) ^ SWZ(rA)) << 3;   // SWZ(r+128)==SWZ(r), so same for all chunks
  const unsigned short* gA  = xb + (size_t)(m0 + rA) * DIM + cs;
  const unsigned short* gB0 = Wt + (size_t)(n0 + rA) * DIM + cs;
  const unsigned short* gB1 = Wt + (size_t)(n0 + rA + 128) * DIM + cs;

  f32x4 acc[4][4] = {};
  gemm_core(gA, gB0, gB1, DIM, DIM, lsA, lsB, 24, wid, lane, acc);

  float bia[4];
#pragma unroll
  for (int n = 0; n < 4; ++n) bia[n] = bias[n0 + wn * 64 + n * 16 + lr];

  if (ntb < 3) {          // Q: * alpha^s / sqrt(d)
#pragma unroll
    for (int f = 0; f < 4; ++f)
#pragma unroll
      for (int r = 0; r < 4; ++r) {
        int mg = m0 + wm * 64 + f * 16 + lg * 4 + r;
        int b = mg >> 10, s = mg & 1023;
        float sc = exp2f((float)s * L2A) * RSQRTD;
        unsigned short* dst = Qs + ((size_t)b * SEQ + s) * DIM + n0 + wn * 64 + lr;
#pragma unroll
        for (int n = 0; n < 4; ++n)
          dst[n * 16] = f2bf((acc[f][n][r] + bia[n]) * sc);
      }
  } else if (ntb < 6) {   // K: * alpha^(-s)
#pragma unroll
    for (int f = 0; f < 4; ++f)
#pragma unroll
      for (int r = 0; r < 4; ++r) {
        int mg = m0 + wm * 64 + f * 16 + lg * 4 + r;
        int b = mg >> 10, s = mg & 1023;
        float sc = exp2f(-(float)s * L2A);
        unsigned short* dst = Ks + ((size_t)b * SEQ + s) * DIM + (n0 - DIM) + wn * 64 + lr;
#pragma unroll
        for (int n = 0; n < 4; ++n)
          dst[n * 16] = f2bf((acc[f][n][r] + bia[n]) * sc);
      }
  } else {                // V: transpose to Vt[b][d][s]
#pragma unroll
    for (int f = 0; f < 4; ++f)
#pragma unroll
      for (int r = 0; r < 4; ++r) {
        int mg = m0 + wm * 64 + f * 16 + lg * 4 + r;
        int b = mg >> 10, s = mg & 1023;
        int d = (n0 - 2 * DIM) + wn * 64 + lr;
        unsigned short* dst = Vt + ((size_t)b * DIM + d) * SEQ + s;
#pragma unroll
        for (int n = 0; n < 4; ++n)
          dst[(size_t)n * 16 * SEQ] = f2bf(acc[f][n][r] + bia[n]);
      }
  }
}

// ---------------- scores: Sm[bl][i][j] = tril(Q' @ K'^T). 20 tiles/batch (i:128, j:256)
__constant__ const signed char IT_TAB[20] = {0,1,2,2,3,3,4,4,4,5,5,5,6,6,6,6,7,7,7,7};
__constant__ const signed char JT_TAB[20] = {0,0,0,1,0,1,0,1,2,0,1,2,0,1,2,3,0,1,2,3};

__global__ void __launch_bounds__(512, 4) score_g(
    const unsigned short* __restrict__ Qs, const unsigned short* __restrict__ Ks,
    unsigned short* __restrict__ Sm, int b_base) {
  __shared__ short lsA[2 * 4096];
  __shared__ short lsB[2 * 8192];
  int idx = blockIdx.x % 20, bl = blockIdx.x / 20;
  int b = b_base + bl;
  int it = IT_TAB[idx], jt = JT_TAB[idx];
  int m0 = it * 128, n0 = jt * 256;
  const unsigned short* A  = Qs + (size_t)b * SEQ * DIM;
  const unsigned short* Bt = Ks + (size_t)b * SEQ * DIM;
  unsigned short* Smp = Sm + (size_t)bl * SEQ * SEQ;

  int tid = threadIdx.x, lane = tid & 63, wid = tid >> 6;
  int wm = wid >> 2, wn = wid & 3;
  int lr = lane & 15, lg = lane >> 4;

  int rA = wid * 16 + (lane >> 2);
  int cs = ((lane & 3) ^ SWZ(rA)) << 3;
  const unsigned short* gA  = A  + (size_t)(m0 + rA) * DIM + cs;
  const unsigned short* gB0 = Bt + (size_t)(n0 + rA) * DIM + cs;
  const unsigned short* gB1 = Bt + (size_t)(n0 + rA + 128) * DIM + cs;

  f32x4 acc[4][4] = {};
  gemm_core(gA, gB0, gB1, DIM, DIM, lsA, lsB, 24, wid, lane, acc);

#pragma unroll
  for (int f = 0; f < 4; ++f)
#pragma unroll
    for (int n = 0; n < 4; ++n) {
      int j = n0 + wn * 64 + n * 16 + lr;
#pragma unroll
      for (int r = 0; r < 4; ++r) {
        int i = m0 + wm * 64 + f * 16 + lg * 4 + r;
        float v = acc[f][n][r];
        if (j > i) v = 0.0f;   // causal mask
        Smp[(size_t)i * SEQ + j] = f2bf(v);
      }
    }
}

// ---------------- PV: out[b][i][d] = Sm[bl] @ V; 24 tiles/batch (i:128, d:256), heavy-first
__global__ void __launch_bounds__(512, 4) pv_g(
    const unsigned short* __restrict__ Sm, const unsigned short* __restrict__ Vt,
    float* __restrict__ out, int b_base) {
  __shared__ short lsA[2 * 4096];
  __shared__ short lsB[2 * 8192];
  int it = 7 - blockIdx.x / 24;          // heavy (large kmax) first
  int rem = blockIdx.x % 24;
  int dt = rem / 8, bl = rem % 8;
  int b = b_base + bl;
  int m0 = it * 128, n0 = dt * 256;
  const unsigned short* A  = Sm + (size_t)bl * SEQ * SEQ;   // ld 1024
  const unsigned short* Bt = Vt + (size_t)b * DIM * SEQ;    // ld 1024
  int nt = (it + 1) * 4;                 // K-tiles of 32, causal bound

  int tid = threadIdx.x, lane = tid & 63, wid = tid >> 6;
  int wm = wid >> 2, wn = wid & 3;
  int lr = lane & 15, lg = lane >> 4;

  int rA = wid * 16 + (lane >> 2);
  int cs = ((lane & 3) ^ SWZ(rA)) << 3;
  const unsigned short* gA  = A  + (size_t)(m0 + rA) * SEQ + cs;
  const unsigned short* gB0 = Bt + (size_t)(n0 + rA) * SEQ + cs;
  const unsigned short* gB1 = Bt + (size_t)(n0 + rA + 128) * SEQ + cs;

  f32x4 acc[4][4] = {};
  gemm_core(gA, gB0, gB1, SEQ, SEQ, lsA, lsB, nt, wid, lane, acc);

#pragma unroll
  for (int f = 0; f < 4; ++f)
#pragma unroll
    for (int n = 0; n < 4; ++n) {
      int d = n0 + wn * 64 + n * 16 + lr;
#pragma unroll
      for (int r = 0; r < 4; ++r) {
        int i = m0 + wm * 64 + f * 16 + lg * 4 + r;
        out[((size_t)b * SEQ + i) * DIM + d] = acc[f][n][r];
      }
    }
}

extern "C" void kernel_launch(void* const* d_in, const int* in_sizes, int n_in,
                              void* d_out, int out_size, void* d_ws, size_t ws_size,
                              hipStream_t stream) {
  const float* x    = (const float*)d_in[0];
  const float* W    = (const float*)d_in[1];
  const float* bias = (const float*)d_in[2];
  float* out = (float*)d_out;

  char* ws = (char*)d_ws;
  // ws: Wt 3.5MB | Qs/Ks/Vt 25.2MB each | Sm 16.8MB (8 batches, reused over 2 groups)
  unsigned short* Wt = (unsigned short*)(ws);
  unsigned short* Qs = (unsigned short*)(ws + 3538944);
  unsigned short* Ks = (unsigned short*)(ws + 3538944 + 25165824);
  unsigned short* Vt = (unsigned short*)(ws + 3538944 + 2 * 25165824);
  unsigned short* Sm = (unsigned short*)(ws + 3538944 + 3 * 25165824);
  // bf16 x lives in d_out (50.3MB >= 25.2MB); fully consumed by qkv_g before pv_g writes.
  unsigned short* xb = (unsigned short*)d_out;

  transpose_w<<<36 * 12, 256, 0, stream>>>(W, Wt);
  convert_x<<<6144, 256, 0, stream>>>(x, xb);
  qkv_g<<<1152, 512, 0, stream>>>(xb, Wt, bias, Qs, Ks, Vt);
  for (int g = 0; g < 2; ++g) {
    score_g<<<GROUP * 20, 512, 0, stream>>>(Qs, Ks, Sm, g * GROUP);
    pv_g<<<GROUP * 24, 512, 0, stream>>>(Sm, Vt, out, g * GROUP);
  }
}

// Round 5
// 149.469 us; speedup vs baseline: 1.7301x; 1.3823x over previous
//
#include <hip/hip_runtime.h>
#include <hip/hip_bf16.h>

// Retention: out = (tril(alpha^(i-j)) * (QK^T/sqrt(d))) @ V, qkv = x@W + b
// Decay folded into operands: Q' = q*alpha^i/sqrt(d), K' = k*alpha^(-j)
// Shared GEMM core: 128x128 tile, BK=64 double-buffered (64KB LDS, 2 blocks/CU),
// 8 waves (32x64/wave, acc[2][4]), global_load_lds w/ pre-swizzled source into
// 128B LDS lines (round-3 geometry: slot = chunk ^ (row&7) -> 0 bank conflicts),
// counted vmcnt(4) gate (waited tile staged one full K-tile earlier), 2 barriers/tile.

#define SEQ   1024
#define DIM   768
#define ND3   2304

typedef __attribute__((ext_vector_type(8))) short bf16x8;
typedef __attribute__((ext_vector_type(4))) float f32x4;

#define L2A     (-0.014499569695115089f)   // log2(0.99)
#define RSQRTD  (0.03608439182435161f)     // 1/sqrt(768)

__device__ __forceinline__ unsigned short f2bf(float x) {
  union { float f; unsigned u; } v; v.f = x;
  unsigned r = v.u + 0x7FFFu + ((v.u >> 16) & 1u);
  return (unsigned short)(r >> 16);
}

__device__ __forceinline__ void gload16(const void* g, void* l) {
  __builtin_amdgcn_global_load_lds(
      (const __attribute__((address_space(1))) void*)g,
      (__attribute__((address_space(3))) void*)l, 16, 0, 0);
}

// ---- core: acc[2][4] += A[128 x nt*64] @ B[128 x nt*64]^T (both row-major, K contig)
// gA/gA2, gB/gB2: per-lane pre-swizzled sources (rows wid*16+l8 and +8), advance 64/tile.
// LDS: [par][128 lines][128B]; line r slot s holds global chunk c = s ^ (r&7).
__device__ __forceinline__ void gemm_core(
    const unsigned short* gA, const unsigned short* gA2,
    const unsigned short* gB, const unsigned short* gB2,
    char* lsA, char* lsB, int nt, int wid, int lane, f32x4 acc[2][4]) {
  int lr = lane & 15, lg = lane >> 4;
  int wm = wid >> 1, wn = wid & 1;
  int rdA = (wm * 32 + lr) * 128 + ((lg ^ (lr & 7)) << 4);
  int rdB = (wn * 64 + lr) * 128 + ((lg ^ (lr & 7)) << 4);
  int wo = wid * 2048;

#define STAGE(t, par) do {                                                    \
    int lo_ = ((par) << 14) + wo;                                             \
    gload16(gA  + (size_t)(t) * 64, lsA + lo_);                               \
    gload16(gA2 + (size_t)(t) * 64, lsA + lo_ + 1024);                        \
    gload16(gB  + (size_t)(t) * 64, lsB + lo_);                               \
    gload16(gB2 + (size_t)(t) * 64, lsB + lo_ + 1024);                        \
  } while (0)

  STAGE(0, 0);
  STAGE(1, 1);
  asm volatile("s_waitcnt vmcnt(4)" ::: "memory");   // tile 0 ready
  __builtin_amdgcn_s_barrier();
  asm volatile("" ::: "memory");

  for (int t = 0; t < nt; ++t) {
    int pbase = (t & 1) << 14;
    bf16x8 aF[2][2], bF[2][4];
#pragma unroll
    for (int kh = 0; kh < 2; ++kh) {
#pragma unroll
      for (int f = 0; f < 2; ++f)
        aF[kh][f] = *(const bf16x8*)(lsA + pbase + ((rdA + f * 2048) ^ (kh << 6)));
#pragma unroll
      for (int n = 0; n < 4; ++n)
        bF[kh][n] = *(const bf16x8*)(lsB + pbase + ((rdB + n * 2048) ^ (kh << 6)));
    }
    __builtin_amdgcn_s_setprio(1);
#pragma unroll
    for (int kh = 0; kh < 2; ++kh)
#pragma unroll
      for (int f = 0; f < 2; ++f)
#pragma unroll
        for (int n = 0; n < 4; ++n)
          acc[f][n] = __builtin_amdgcn_mfma_f32_16x16x32_bf16(aF[kh][f], bF[kh][n], acc[f][n], 0, 0, 0);
    __builtin_amdgcn_s_setprio(0);

    if (t == nt - 1) break;
    __builtin_amdgcn_s_barrier();                    // all reads of this parity done
    asm volatile("" ::: "memory");
    if (t + 2 < nt) {
      STAGE(t + 2, t & 1);                           // refill buffer tile t used
      asm volatile("s_waitcnt vmcnt(4)" ::: "memory");  // tile t+1 ready (counted)
    } else {
      asm volatile("s_waitcnt vmcnt(0)" ::: "memory");  // drain last tile
    }
    __builtin_amdgcn_s_barrier();
    asm volatile("" ::: "memory");
  }
#undef STAGE
}

// ---------------- x f32 -> bf16, vectorized
__global__ void convert_x(const float* __restrict__ x, unsigned short* __restrict__ xb) {
  size_t i = ((size_t)blockIdx.x * 256 + threadIdx.x) * 8;
  float4 f0 = *(const float4*)(x + i);
  float4 f1 = *(const float4*)(x + i + 4);
  bf16x8 v;
  v[0] = (short)f2bf(f0.x); v[1] = (short)f2bf(f0.y);
  v[2] = (short)f2bf(f0.z); v[3] = (short)f2bf(f0.w);
  v[4] = (short)f2bf(f1.x); v[5] = (short)f2bf(f1.y);
  v[6] = (short)f2bf(f1.z); v[7] = (short)f2bf(f1.w);
  *(bf16x8*)(xb + i) = v;
}

// ---------------- W transpose+convert: W[768][2304] f32 -> Wt[2304][768] bf16
__global__ void transpose_w(const float* __restrict__ W, unsigned short* __restrict__ Wt) {
  __shared__ float tile[64][65];
  int n0 = (blockIdx.x % 36) * 64;
  int k0 = (blockIdx.x / 36) * 64;
  int tx = threadIdx.x & 63, ty = threadIdx.x >> 6;
#pragma unroll
  for (int p = 0; p < 16; ++p) {
    int k = ty + p * 4;
    tile[k][tx] = W[(size_t)(k0 + k) * ND3 + n0 + tx];
  }
  __syncthreads();
#pragma unroll
  for (int p = 0; p < 16; ++p) {
    int n = ty + p * 4;
    Wt[(size_t)(n0 + n) * DIM + k0 + tx] = f2bf(tile[tx][n]);
  }
}

// ---------------- QKV: xb[16384][768] @ Wt^T -> Q',K',Vt. grid 2304 = 128mt x 18nt
__global__ void __launch_bounds__(512, 4) qkv_g(
    const unsigned short* __restrict__ xb, const unsigned short* __restrict__ Wt,
    const float* __restrict__ bias,
    unsigned short* __restrict__ Qs, unsigned short* __restrict__ Ks,
    unsigned short* __restrict__ Vt) {
  __shared__ char lsA[32768];
  __shared__ char lsB[32768];
  int bid = (blockIdx.x & 7) * 288 + (blockIdx.x >> 3);   // bijective XCD swizzle
  int mt = bid / 18, ntb = bid % 18;
  int m0 = mt * 128, n0 = ntb * 128;

  int tid = threadIdx.x, lane = tid & 63, wid = tid >> 6;
  int l8 = lane >> 3, cs = ((lane & 7) ^ l8) << 3;        // pre-swizzled chunk col
  int srow = wid * 16 + l8;

  const unsigned short* gA = xb + (size_t)(m0 + srow) * DIM + cs;
  const unsigned short* gB = Wt + (size_t)(n0 + srow) * DIM + cs;

  f32x4 acc[2][4] = {};
  gemm_core(gA, gA + 8 * DIM, gB, gB + 8 * DIM, lsA, lsB, 12, wid, lane, acc);

  int wm = wid >> 1, wn = wid & 1;
  int lr = lane & 15, lg = lane >> 4;
  float bia[4];
#pragma unroll
  for (int n = 0; n < 4; ++n) bia[n] = bias[n0 + wn * 64 + n * 16 + lr];

  if (ntb < 6) {           // Q: * alpha^s / sqrt(d)
#pragma unroll
    for (int f = 0; f < 2; ++f)
#pragma unroll
      for (int r = 0; r < 4; ++r) {
        int mg = m0 + wm * 32 + f * 16 + lg * 4 + r;
        int b = mg >> 10, s = mg & 1023;
        float sc = exp2f((float)s * L2A) * RSQRTD;
        unsigned short* dst = Qs + ((size_t)b * SEQ + s) * DIM + n0 + wn * 64 + lr;
#pragma unroll
        for (int n = 0; n < 4; ++n)
          dst[n * 16] = f2bf((acc[f][n][r] + bia[n]) * sc);
      }
  } else if (ntb < 12) {   // K: * alpha^(-s)
#pragma unroll
    for (int f = 0; f < 2; ++f)
#pragma unroll
      for (int r = 0; r < 4; ++r) {
        int mg = m0 + wm * 32 + f * 16 + lg * 4 + r;
        int b = mg >> 10, s = mg & 1023;
        float sc = exp2f(-(float)s * L2A);
        unsigned short* dst = Ks + ((size_t)b * SEQ + s) * DIM + (n0 - DIM) + wn * 64 + lr;
#pragma unroll
        for (int n = 0; n < 4; ++n)
          dst[n * 16] = f2bf((acc[f][n][r] + bia[n]) * sc);
      }
  } else {                 // V: transpose to Vt[b][d][s]
#pragma unroll
    for (int f = 0; f < 2; ++f)
#pragma unroll
      for (int r = 0; r < 4; ++r) {
        int mg = m0 + wm * 32 + f * 16 + lg * 4 + r;
        int b = mg >> 10, s = mg & 1023;
        int d = (n0 - 2 * DIM) + wn * 64 + lr;
        unsigned short* dst = Vt + ((size_t)b * DIM + d) * SEQ + s;
#pragma unroll
        for (int n = 0; n < 4; ++n)
          dst[(size_t)n * 16 * SEQ] = f2bf(acc[f][n][r] + bia[n]);
      }
  }
}

// ---------------- scores: Sm[bl][i][j] = tril(Q' @ K'^T). 36 lower-tri 128x128 tiles/batch
__global__ void __launch_bounds__(512, 4) score_g(
    const unsigned short* __restrict__ Qs, const unsigned short* __restrict__ Ks,
    unsigned short* __restrict__ Sm, int b_base) {
  __shared__ char lsA[32768];
  __shared__ char lsB[32768];
  int bid = (blockIdx.x & 7) * (gridDim.x >> 3) + (blockIdx.x >> 3);
  int t = bid % 36, bl = bid / 36;
  int b = b_base + bl;
  int it = 0;
  while (t >= it + 1) { t -= it + 1; it++; }
  int jt = t;
  int m0 = it * 128, n0 = jt * 128;
  const unsigned short* A  = Qs + (size_t)b * SEQ * DIM;
  const unsigned short* Bt = Ks + (size_t)b * SEQ * DIM;
  unsigned short* Smp = Sm + (size_t)bl * SEQ * SEQ;

  int tid = threadIdx.x, lane = tid & 63, wid = tid >> 6;
  int l8 = lane >> 3, cs = ((lane & 7) ^ l8) << 3;
  int srow = wid * 16 + l8;

  const unsigned short* gA = A  + (size_t)(m0 + srow) * DIM + cs;
  const unsigned short* gB = Bt + (size_t)(n0 + srow) * DIM + cs;

  f32x4 acc[2][4] = {};
  gemm_core(gA, gA + 8 * DIM, gB, gB + 8 * DIM, lsA, lsB, 12, wid, lane, acc);

  int wm = wid >> 1, wn = wid & 1;
  int lr = lane & 15, lg = lane >> 4;
#pragma unroll
  for (int f = 0; f < 2; ++f)
#pragma unroll
    for (int n = 0; n < 4; ++n) {
      int j = n0 + wn * 64 + n * 16 + lr;
#pragma unroll
      for (int r = 0; r < 4; ++r) {
        int i = m0 + wm * 32 + f * 16 + lg * 4 + r;
        float v = acc[f][n][r];
        if (j > i) v = 0.0f;   // causal mask (bites only on diagonal tiles)
        Smp[(size_t)i * SEQ + j] = f2bf(v);
      }
    }
}

// ---------------- PV: out[b][i][d] = Sm[bl] @ V; tiles (i:128, d:128), heavy-first
__global__ void __launch_bounds__(512, 4) pv_g(
    const unsigned short* __restrict__ Sm, const unsigned short* __restrict__ Vt,
    float* __restrict__ out, int b_base, int gsz) {
  __shared__ char lsA[32768];
  __shared__ char lsB[32768];
  int it = 7 - blockIdx.x / (gsz * 6);     // heavy (large kmax) first
  int rem = blockIdx.x % (gsz * 6);
  int bl = rem / 6, dt = rem % 6;
  int b = b_base + bl;
  int m0 = it * 128, n0 = dt * 128;
  const unsigned short* A  = Sm + (size_t)bl * SEQ * SEQ;   // ld 1024
  const unsigned short* Bt = Vt + (size_t)b * DIM * SEQ;    // ld 1024
  int nt = (it + 1) * 2;                   // K-tiles of 64, causal bound (>=2)

  int tid = threadIdx.x, lane = tid & 63, wid = tid >> 6;
  int l8 = lane >> 3, cs = ((lane & 7) ^ l8) << 3;
  int srow = wid * 16 + l8;

  const unsigned short* gA = A  + (size_t)(m0 + srow) * SEQ + cs;
  const unsigned short* gB = Bt + (size_t)(n0 + srow) * SEQ + cs;

  f32x4 acc[2][4] = {};
  gemm_core(gA, gA + 8 * SEQ, gB, gB + 8 * SEQ, lsA, lsB, nt, wid, lane, acc);

  int wm = wid >> 1, wn = wid & 1;
  int lr = lane & 15, lg = lane >> 4;
#pragma unroll
  for (int f = 0; f < 2; ++f)
#pragma unroll
    for (int n = 0; n < 4; ++n) {
      int d = n0 + wn * 64 + n * 16 + lr;
#pragma unroll
      for (int r = 0; r < 4; ++r) {
        int i = m0 + wm * 32 + f * 16 + lg * 4 + r;
        out[((size_t)b * SEQ + i) * DIM + d] = acc[f][n][r];
      }
    }
}

extern "C" void kernel_launch(void* const* d_in, const int* in_sizes, int n_in,
                              void* d_out, int out_size, void* d_ws, size_t ws_size,
                              hipStream_t stream) {
  const float* x    = (const float*)d_in[0];
  const float* W    = (const float*)d_in[1];
  const float* bias = (const float*)d_in[2];
  float* out = (float*)d_out;

  char* ws = (char*)d_ws;
  // ws: Wt 3.5MB | Qs/Ks/Vt 25.2MB each | Sm 16.8MB (8 batches) or 33.6MB (16, if ws fits)
  unsigned short* Wt = (unsigned short*)(ws);
  unsigned short* Qs = (unsigned short*)(ws + 3538944);
  unsigned short* Ks = (unsigned short*)(ws + 3538944 + 25165824);
  unsigned short* Vt = (unsigned short*)(ws + 3538944 + 2 * 25165824);
  unsigned short* Sm = (unsigned short*)(ws + 3538944 + 3 * 25165824);
  // bf16 x lives in d_out (50.3MB >= 25.2MB); fully consumed by qkv_g before pv_g writes.
  unsigned short* xb = (unsigned short*)d_out;

  size_t smBase = 3538944 + 3 * (size_t)25165824;
  int gsz = (ws_size >= smBase + (size_t)16 * SEQ * SEQ * 2) ? 16 : 8;
  int ngrp = 16 / gsz;

  transpose_w<<<36 * 12, 256, 0, stream>>>(W, Wt);
  convert_x<<<6144, 256, 0, stream>>>(x, xb);
  qkv_g<<<2304, 512, 0, stream>>>(xb, Wt, bias, Qs, Ks, Vt);
  for (int g = 0; g < ngrp; ++g) {
    score_g<<<gsz * 36, 512, 0, stream>>>(Qs, Ks, Sm, g * gsz);
    pv_g<<<gsz * 48, 512, 0, stream>>>(Sm, Vt, out, g * gsz, gsz);
  }
}